// Round 10
// baseline (185.740 us; speedup 1.0000x reference)
//
#include <hip/hip_runtime.h>

#define NM 23        // 3*K - 1, K = 8

__device__ __forceinline__ float softplus_f(float v) {
  // stable: max(v,0) + log(1 + exp(-|v|))
  return fmaxf(v, 0.f) + __logf(1.f + __expf(-fabsf(v)));
}

// ---------------------------------------------------------------------------
// SINGLE fused kernel, no workspace, no prep. 64 rows/block, 1024 threads
// (16 waves), lane = row. Grid = B/64 = 512.
//
// Gap-theory test: rounds 1-9 show ~50-75us of non-dispatch time whenever
// the launch uses 2+ kernels + d_ws (R2's single-kernel round had gap ~0).
// This kernel eliminates both: one dispatch, d_ws untouched.
//
// Masking strategy (no prepped weights):
//   L1/L2: inline uniform selects on raw W1/W2 (R8-proven code; small layers,
//          ~384 selects/thread is negligible).
//   L3:    mask h2 instead of W3: h2m[k] = (k<d)?h2[k]:0 -- 32 selects per d
//          (R3's disaster was 736 weight-selects per d). m-outer/k-inner on
//          RAW W3 rows (contiguous 32 floats per (m,d) -> s_load_dwordx8).
// ---------------------------------------------------------------------------
__global__ __launch_bounds__(1024, 4) void fused_kernel(
    const float* __restrict__ x,
    const float* __restrict__ W1, const float* __restrict__ b1,
    const float* __restrict__ W2, const float* __restrict__ b2,
    const float* __restrict__ W3, const float* __restrict__ b3,
    float* __restrict__ out, int B) {
  __shared__ float xs[64][65];    // x tile, kept through spline
  __shared__ float h1s[64][65];   // h1; reused as z staging after layer 2
  __shared__ float h2s[64][33];
  __shared__ float ldp[16][64];

  const int t = threadIdx.x;
  const int b0 = blockIdx.x * 64;

  // ---- stage x tile: one float4 per thread (1024 thr = 64x64) ----
  {
    const int rr = t >> 4, c4 = (t & 15) * 4;
    const float4 v =
        *reinterpret_cast<const float4*>(x + (size_t)b0 * 64 + (size_t)t * 4);
    xs[rr][c4 + 0] = v.x; xs[rr][c4 + 1] = v.y;
    xs[rr][c4 + 2] = v.z; xs[rr][c4 + 3] = v.w;
  }
  __syncthreads();

  const int r  = t & 63;                                  // lane = row
  const int wv = __builtin_amdgcn_readfirstlane(t >> 6);  // wave 0..15

  // ---- layer 1: h1[r][i], i in [wv*4, wv*4+4); mask (dd < (i%63)+1) ----
  {
    float acc1[4];
    #pragma unroll
    for (int ii = 0; ii < 4; ++ii) acc1[ii] = b1[wv * 4 + ii];
    #pragma unroll 4
    for (int dd = 0; dd < 64; ++dd) {
      const float xv = xs[r][dd];
      #pragma unroll
      for (int ii = 0; ii < 4; ++ii) {
        const int i = wv * 4 + ii;
        const int deg = (i % 63) + 1;                       // uniform
        const float w = (dd < deg) ? W1[i * 64 + dd] : 0.f; // uniform select
        acc1[ii] = fmaf(xv, w, acc1[ii]);
      }
    }
    #pragma unroll
    for (int ii = 0; ii < 4; ++ii) h1s[r][wv * 4 + ii] = fmaxf(acc1[ii], 0.f);
  }
  __syncthreads();

  // ---- layer 2: h2[r][j], j in [wv*2, wv*2+2); mask (i<=j || i==63) ----
  {
    float acc2[2];
    #pragma unroll
    for (int jj = 0; jj < 2; ++jj) acc2[jj] = b2[wv * 2 + jj];
    #pragma unroll 4
    for (int i2 = 0; i2 < 64; ++i2) {
      const float hv = h1s[r][i2];
      #pragma unroll
      for (int jj = 0; jj < 2; ++jj) {
        const int j = wv * 2 + jj;
        const bool on = (i2 <= j) || (i2 == 63);            // uniform
        const float w = on ? W2[j * 64 + i2] : 0.f;         // uniform select
        acc2[jj] = fmaf(hv, w, acc2[jj]);
      }
    }
    #pragma unroll
    for (int jj = 0; jj < 2; ++jj)
      h2s[r][wv * 2 + jj] = fmaxf(acc2[jj], 0.f);
  }
  __syncthreads();   // h2s ready; h1s dead -> reusable as z staging

  float ldacc = 0.f;

  // ---- layer 3 + spline: 4 d's per thread (d = wv*4+di) ----
  #pragma unroll 1
  for (int di = 0; di < 4; ++di) {
    const int dU = __builtin_amdgcn_readfirstlane(wv * 4 + di);

    // masked h2 in registers: h2m[k] = (k < dU) ? h2[k] : 0
    // wv>=8 => dU>=32 => mask full, plain copy (uniform branch)
    float h2m[32];
    if (wv >= 8) {
      #pragma unroll
      for (int k = 0; k < 32; ++k) h2m[k] = h2s[r][k];
    } else {
      #pragma unroll
      for (int k = 0; k < 32; ++k)
        h2m[k] = (k < dU) ? h2s[r][k] : 0.f;
    }

    // m-outer / k-inner on RAW W3: row (m*64+dU) is 32 contiguous floats
    float p[NM];
    #pragma unroll
    for (int m = 0; m < NM; ++m) {
      const float* wrow = W3 + ((size_t)(m * 64 + dU)) * 32;  // uniform
      float acc = b3[m * 64 + dU];
      #pragma unroll
      for (int kk = 0; kk < 32; ++kk)
        acc = fmaf(h2m[kk], wrow[kk], acc);
      p[m] = acc;
    }

    const float xv = xs[r][dU];
    const float xc = fminf(fmaxf(xv, -3.f), 3.f);

    // softmax over widths logits p[0..7]
    float mw = p[0];
    #pragma unroll
    for (int k = 1; k < 8; ++k) mw = fmaxf(mw, p[k]);
    float ew[8], sw = 0.f;
    #pragma unroll
    for (int k = 0; k < 8; ++k) { ew[k] = __expf(p[k] - mw); sw += ew[k]; }
    const float invw = 1.f / sw;

    // softmax over heights logits p[8..15]
    float mh = p[8];
    #pragma unroll
    for (int k = 1; k < 8; ++k) mh = fmaxf(mh, p[8 + k]);
    float eh[8], sh = 0.f;
    #pragma unroll
    for (int k = 0; k < 8; ++k) { eh[k] = __expf(p[8 + k] - mh); sh += eh[k]; }
    const float invh = 1.f / sh;

    const float WSC = 1.0f - 1e-3f * 8.0f;   // 1 - MIN_BIN_WIDTH*K
    float cumw[9], cumh[9];
    cumw[0] = -3.f; cumh[0] = -3.f;
    float cw = 0.f, ch = 0.f;
    #pragma unroll
    for (int k = 0; k < 7; ++k) {
      cw += 1e-3f + WSC * (ew[k] * invw);
      ch += 1e-3f + WSC * (eh[k] * invh);
      cumw[k + 1] = fmaf(6.f, cw, -3.f);
      cumh[k + 1] = fmaf(6.f, ch, -3.f);
    }
    cumw[8] = 3.f; cumh[8] = 3.f;

    float derivs[9];
    derivs[0] = 1.f; derivs[8] = 1.f;
    #pragma unroll
    for (int k = 0; k < 7; ++k) derivs[k + 1] = 1e-3f + softplus_f(p[16 + k]);

    // bin select: idx = sum(xc >= cumw[k]+EPS) - 1, clipped to [0,7]
    float xk = cumw[0], xk1 = cumw[1];
    float yk = cumh[0], yk1 = cumh[1];
    float dk = derivs[0], dk1 = derivs[1];
    #pragma unroll
    for (int k = 1; k < 8; ++k) {
      const bool s = xc >= cumw[k] + 1e-6f;
      xk  = s ? cumw[k]       : xk;
      xk1 = s ? cumw[k + 1]   : xk1;
      yk  = s ? cumh[k]       : yk;
      yk1 = s ? cumh[k + 1]   : yk1;
      dk  = s ? derivs[k]     : dk;
      dk1 = s ? derivs[k + 1] : dk1;
    }

    const float wk = xk1 - xk, hk = yk1 - yk;
    const float invwk = 1.f / wk;
    const float delta = hk * invwk;
    const float theta = (xc - xk) * invwk;
    const float omt = 1.f - theta;
    const float tt = theta * omt;
    const float th2 = theta * theta;
    const float num = hk * (delta * th2 + dk * tt);
    const float den = delta + (dk + dk1 - 2.f * delta) * tt;
    const float yv = yk + num / den;
    const float dnum = delta * delta * (dk1 * th2 + 2.f * delta * tt + dk * omt * omt);
    const float ldv = __logf(dnum) - 2.f * __logf(den);

    const bool inside = (xv >= -3.f) && (xv <= 3.f);
    h1s[r][dU] = inside ? yv : xv;           // z staging in dead h1s
    ldacc += inside ? ldv : 0.f;
  }

  ldp[wv][r] = ldacc;
  __syncthreads();

  // ---- coalesced z write: one float4 per thread ----
  {
    const int rr = t >> 4, c4 = (t & 15) * 4;
    const float4 v = make_float4(h1s[rr][c4 + 0], h1s[rr][c4 + 1],
                                 h1s[rr][c4 + 2], h1s[rr][c4 + 3]);
    *reinterpret_cast<float4*>(out + (size_t)b0 * 64 + (size_t)t * 4) = v;
  }
  // ---- per-row log-det: complete within block, direct store ----
  if (t < 64) {
    float s = 0.f;
    #pragma unroll
    for (int w = 0; w < 16; ++w) s += ldp[w][t];
    out[(size_t)B * 64 + b0 + t] = s;
  }
}

extern "C" void kernel_launch(void* const* d_in, const int* in_sizes, int n_in,
                              void* d_out, int out_size, void* d_ws, size_t ws_size,
                              hipStream_t stream) {
  const float* x  = (const float*)d_in[0];
  const float* W1 = (const float*)d_in[1];
  const float* b1 = (const float*)d_in[2];
  const float* W2 = (const float*)d_in[3];
  const float* b2 = (const float*)d_in[4];
  const float* W3 = (const float*)d_in[5];
  const float* b3 = (const float*)d_in[6];
  float* out = (float*)d_out;

  const int B = in_sizes[0] / 64;        // 32768

  fused_kernel<<<B / 64, 1024, 0, stream>>>(
      x, W1, b1, W2, b2, W3, b3, out, B);
}

// Round 11
// 153.689 us; speedup vs baseline: 1.2085x; 1.2085x over previous
//
#include <hip/hip_runtime.h>

#define NM 23        // 3*K - 1, K = 8

typedef short short8 __attribute__((ext_vector_type(8)));
typedef float f32x4 __attribute__((ext_vector_type(4)));

__device__ __forceinline__ float softplus_f(float v) {
  return fmaxf(v, 0.f) + __logf(1.f + __expf(-fabsf(v)));
}

__device__ __forceinline__ unsigned short bf16_rne(float x) {
  unsigned u = __float_as_uint(x);
  u += 0x7FFFu + ((u >> 16) & 1u);
  return (unsigned short)(u >> 16);
}

// ---------------------------------------------------------------------------
// Prep: pre-masked L1/L2 weights (R9-proven) + W3 as MFMA B-fragments.
// B operand layout for mfma_f32_16x16x32_bf16: B[k][n], n=lane&15,
// k=(lane>>4)*8+j (mirror of the m120-verified A layout). Column ordering is
// m-major: n = m*64 + d  => tile nt covers m=nt>>2, d in [(nt&3)*16, +16).
// Stored lane-contiguous: Bfrag[nt][lane][j] (16B per lane -> dwordx4 load).
// hi/lo bf16 split for ~fp32 accuracy. Coverage: 184*256 = 47104 exact.
// ---------------------------------------------------------------------------
__global__ __launch_bounds__(256) void prep_kernel(
    const float* __restrict__ W1, const float* __restrict__ W2,
    const float* __restrict__ W3,
    float* __restrict__ W1t, float* __restrict__ W2t,
    unsigned short* __restrict__ Bhi, unsigned short* __restrict__ Blo) {
  const int idx = blockIdx.x * 256 + threadIdx.x;
  if (idx < 64 * 64) {                  // W1t[d][i] = mask * W1[i][d]
    const int d = idx >> 6, i = idx & 63;
    W1t[idx] = ((i % 63) >= d) ? W1[i * 64 + d] : 0.f;
  }
  if (idx < 64 * 32) {                  // W2t[i][j] = mask * W2[j][i]
    const int i = idx >> 5, j = idx & 31;
    W2t[idx] = ((i % 63) <= j) ? W2[j * 64 + i] : 0.f;
  }
  if (idx < 92 * 64 * 8) {              // B fragments
    const int nt = idx >> 9;            // tile
    const int rem = idx & 511;
    const int lane = rem >> 3, j = rem & 7;
    const int col = lane & 15, quad = lane >> 4;
    const int n = nt * 16 + col;        // n = m*64 + d
    const int d = n & 63;
    const int k = quad * 8 + j;
    const float v = (k < d) ? W3[(size_t)n * 32 + k] : 0.f;  // MADE mask k<d
    const unsigned short h = bf16_rne(v);
    const float hf = __uint_as_float(((unsigned)h) << 16);
    Bhi[idx] = h;
    Blo[idx] = bf16_rne(v - hf);
  }
}

// ---------------------------------------------------------------------------
// Fused kernel: 64 rows/block, 512 threads (8 waves), grid = B/64 = 512.
// L1/L2: lane=row, pure fmac on pre-masked transposed weights (R9-proven).
// L3: MFMA. Wave w -> M-tile mt=w&3 (A-frag from h2, loaded once, bf16 hi/lo
// split), d-chunks dc = (w>>2)*2 + {0,1}. Per (mt,dc): 23 tiles (one per m),
// 3 MFMAs each. C layout (m89/m91-verified): row=quad*4+reg, col=lane&15 =>
// after 23 tiles each lane holds p[m=0..22] for 4 rows x 1 d IN REGISTERS --
// spline consumes accumulators directly, no LDS round-trip.
// launch_bounds(512,4): 2 blocks/CU (16 waves), VGPR cap 128.
// ---------------------------------------------------------------------------
__global__ __launch_bounds__(512, 4) void fused_kernel(
    const float* __restrict__ x,
    const float* __restrict__ W1t, const float* __restrict__ b1,
    const float* __restrict__ W2t, const float* __restrict__ b2,
    const unsigned short* __restrict__ Bhi,
    const unsigned short* __restrict__ Blo,
    const float* __restrict__ b3,
    float* __restrict__ out, int B) {
  __shared__ float xs[64][68];     // x in, z in-place (stride 68: 16B-aligned)
  __shared__ float h1s[64][68];
  __shared__ float h2s[64][36];    // stride 36: aligned b128 A-frag reads
  __shared__ float b3s[64 * NM];   // b3s[d*23+m] = b3[m*64+d]
  __shared__ float ld_s[2][64];

  const int t = threadIdx.x;
  const int b0 = blockIdx.x * 64;

  // ---- stage x: 2 float4/thread, coalesced ----
  #pragma unroll
  for (int u = 0; u < 2; ++u) {
    const int idx = t + u * 512;
    const int rr = idx >> 4, c4 = (idx & 15) * 4;
    const float4 v = *reinterpret_cast<const float4*>(
        x + (size_t)b0 * 64 + (size_t)idx * 4);
    xs[rr][c4 + 0] = v.x; xs[rr][c4 + 1] = v.y;
    xs[rr][c4 + 2] = v.z; xs[rr][c4 + 3] = v.w;
  }
  // ---- stage b3s ----
  for (int idx = t; idx < 64 * NM; idx += 512) {
    const int d = idx / NM, m = idx - d * NM;
    b3s[idx] = b3[m * 64 + d];
  }
  __syncthreads();

  const int r  = t & 63;                                  // lane = row
  const int wv = __builtin_amdgcn_readfirstlane(t >> 6);  // wave 0..7

  // ---- layer 1: i in [wv*8, wv*8+8), pure fmac ----
  {
    const int iBase = wv * 8;
    float acc1[8];
    #pragma unroll
    for (int ii = 0; ii < 8; ++ii) acc1[ii] = b1[iBase + ii];
    #pragma unroll 8
    for (int dd = 0; dd < 64; ++dd) {
      const float xv = xs[r][dd];
      const float* wrow = W1t + dd * 64 + iBase;          // dwordx8 s_load
      #pragma unroll
      for (int ii = 0; ii < 8; ++ii) acc1[ii] = fmaf(xv, wrow[ii], acc1[ii]);
    }
    #pragma unroll
    for (int ii = 0; ii < 8; ++ii) h1s[r][iBase + ii] = fmaxf(acc1[ii], 0.f);
  }
  __syncthreads();

  // ---- layer 2: j in [wv*4, wv*4+4), pure fmac ----
  {
    const int jBase = wv * 4;
    float acc2[4];
    #pragma unroll
    for (int jj = 0; jj < 4; ++jj) acc2[jj] = b2[jBase + jj];
    #pragma unroll 8
    for (int i2 = 0; i2 < 64; ++i2) {
      const float hv = h1s[r][i2];
      const float* wrow = W2t + i2 * 32 + jBase;          // dwordx4 s_load
      #pragma unroll
      for (int jj = 0; jj < 4; ++jj) acc2[jj] = fmaf(hv, wrow[jj], acc2[jj]);
    }
    #pragma unroll
    for (int jj = 0; jj < 4; ++jj)
      h2s[r][jBase + jj] = fmaxf(acc2[jj], 0.f);
  }
  __syncthreads();

  // ---- MFMA layer 3 + spline ----
  const int lane = t & 63;
  const int mt   = wv & 3;              // M-tile (rows mt*16..mt*16+15)
  const int col  = lane & 15;
  const int quad = lane >> 4;

  // A fragment: A[m=lane&15][k=quad*8+j] from h2, bf16 hi/lo split
  short8 ahi, alo;
  {
    const int arow = mt * 16 + col;
    const f32x4 a0 = *reinterpret_cast<const f32x4*>(&h2s[arow][quad * 8]);
    const f32x4 a1 = *reinterpret_cast<const f32x4*>(&h2s[arow][quad * 8 + 4]);
    float af[8] = {a0.x, a0.y, a0.z, a0.w, a1.x, a1.y, a1.z, a1.w};
    #pragma unroll
    for (int j = 0; j < 8; ++j) {
      const unsigned short h = bf16_rne(af[j]);
      ahi[j] = (short)h;
      alo[j] = (short)bf16_rne(af[j] - __uint_as_float(((unsigned)h) << 16));
    }
  }

  float ldr[4] = {0.f, 0.f, 0.f, 0.f};

  #pragma unroll 1
  for (int jj = 0; jj < 2; ++jj) {
    const int dc = (wv >> 2) * 2 + jj;                    // d-chunk 0..3
    const int d  = dc * 16 + col;                         // this lane's d

    f32x4 acc[NM];
    #pragma unroll
    for (int m = 0; m < NM; ++m) acc[m] = (f32x4){0.f, 0.f, 0.f, 0.f};
    #pragma unroll
    for (int m = 0; m < NM; ++m) {
      const int nt = 4 * m + dc;
      const size_t off = ((size_t)nt * 64 + lane) * 8;
      const short8 bh = *reinterpret_cast<const short8*>(Bhi + off);
      const short8 bl = *reinterpret_cast<const short8*>(Blo + off);
      acc[m] = __builtin_amdgcn_mfma_f32_16x16x32_bf16(ahi, bh, acc[m], 0, 0, 0);
      acc[m] = __builtin_amdgcn_mfma_f32_16x16x32_bf16(alo, bh, acc[m], 0, 0, 0);
      acc[m] = __builtin_amdgcn_mfma_f32_16x16x32_bf16(ahi, bl, acc[m], 0, 0, 0);
    }

    // spline: 4 rows per lane (C rows quad*4+reg), this lane's d
    #pragma unroll
    for (int reg = 0; reg < 4; ++reg) {
      const int row = mt * 16 + quad * 4 + reg;

      float p[NM];
      #pragma unroll
      for (int m = 0; m < NM; ++m) p[m] = acc[m][reg] + b3s[d * NM + m];

      const float xv = xs[row][d];
      const float xc = fminf(fmaxf(xv, -3.f), 3.f);

      float mw = p[0];
      #pragma unroll
      for (int k = 1; k < 8; ++k) mw = fmaxf(mw, p[k]);
      float ew[8], sw = 0.f;
      #pragma unroll
      for (int k = 0; k < 8; ++k) { ew[k] = __expf(p[k] - mw); sw += ew[k]; }
      const float invw = 1.f / sw;

      float mh = p[8];
      #pragma unroll
      for (int k = 1; k < 8; ++k) mh = fmaxf(mh, p[8 + k]);
      float eh[8], sh = 0.f;
      #pragma unroll
      for (int k = 0; k < 8; ++k) { eh[k] = __expf(p[8 + k] - mh); sh += eh[k]; }
      const float invh = 1.f / sh;

      const float WSC = 1.0f - 1e-3f * 8.0f;
      float cumw[9], cumh[9];
      cumw[0] = -3.f; cumh[0] = -3.f;
      float cw = 0.f, ch = 0.f;
      #pragma unroll
      for (int k = 0; k < 7; ++k) {
        cw += 1e-3f + WSC * (ew[k] * invw);
        ch += 1e-3f + WSC * (eh[k] * invh);
        cumw[k + 1] = fmaf(6.f, cw, -3.f);
        cumh[k + 1] = fmaf(6.f, ch, -3.f);
      }
      cumw[8] = 3.f; cumh[8] = 3.f;

      float derivs[9];
      derivs[0] = 1.f; derivs[8] = 1.f;
      #pragma unroll
      for (int k = 0; k < 7; ++k) derivs[k + 1] = 1e-3f + softplus_f(p[16 + k]);

      float xk = cumw[0], xk1 = cumw[1];
      float yk = cumh[0], yk1 = cumh[1];
      float dk = derivs[0], dk1 = derivs[1];
      #pragma unroll
      for (int k = 1; k < 8; ++k) {
        const bool s = xc >= cumw[k] + 1e-6f;
        xk  = s ? cumw[k]       : xk;
        xk1 = s ? cumw[k + 1]   : xk1;
        yk  = s ? cumh[k]       : yk;
        yk1 = s ? cumh[k + 1]   : yk1;
        dk  = s ? derivs[k]     : dk;
        dk1 = s ? derivs[k + 1] : dk1;
      }

      const float wk = xk1 - xk, hk = yk1 - yk;
      const float invwk = 1.f / wk;
      const float delta = hk * invwk;
      const float theta = (xc - xk) * invwk;
      const float omt = 1.f - theta;
      const float tt = theta * omt;
      const float th2 = theta * theta;
      const float num = hk * (delta * th2 + dk * tt);
      const float den = delta + (dk + dk1 - 2.f * delta) * tt;
      const float yv = yk + num / den;
      const float dnum = delta * delta * (dk1 * th2 + 2.f * delta * tt + dk * omt * omt);
      const float ldv = __logf(dnum) - 2.f * __logf(den);

      const bool inside = (xv >= -3.f) && (xv <= 3.f);
      xs[row][d] = inside ? yv : xv;        // z in-place (same owner)
      ldr[reg] += inside ? ldv : 0.f;
    }
  }

  // ---- log-det: reduce over the 16 cols sharing each row-group ----
  #pragma unroll
  for (int mask = 1; mask <= 8; mask <<= 1) {
    #pragma unroll
    for (int reg = 0; reg < 4; ++reg)
      ldr[reg] += __shfl_xor(ldr[reg], mask, 64);
  }
  if (col == 0) {
    #pragma unroll
    for (int reg = 0; reg < 4; ++reg)
      ld_s[wv >> 2][mt * 16 + quad * 4 + reg] = ldr[reg];
  }
  __syncthreads();

  // ---- coalesced z write ----
  #pragma unroll
  for (int u = 0; u < 2; ++u) {
    const int idx = t + u * 512;
    const int rr = idx >> 4, c4 = (idx & 15) * 4;
    const float4 v = make_float4(xs[rr][c4 + 0], xs[rr][c4 + 1],
                                 xs[rr][c4 + 2], xs[rr][c4 + 3]);
    *reinterpret_cast<float4*>(out + (size_t)b0 * 64 + (size_t)idx * 4) = v;
  }
  // ---- log-det out ----
  if (t < 64) {
    out[(size_t)B * 64 + b0 + t] = ld_s[0][t] + ld_s[1][t];
  }
}

extern "C" void kernel_launch(void* const* d_in, const int* in_sizes, int n_in,
                              void* d_out, int out_size, void* d_ws, size_t ws_size,
                              hipStream_t stream) {
  const float* x  = (const float*)d_in[0];
  const float* W1 = (const float*)d_in[1];
  const float* b1 = (const float*)d_in[2];
  const float* W2 = (const float*)d_in[3];
  const float* b2 = (const float*)d_in[4];
  const float* W3 = (const float*)d_in[5];
  const float* b3 = (const float*)d_in[6];
  float* out = (float*)d_out;
  char* ws   = (char*)d_ws;

  float* W1t = (float*)ws;                              // 4096 f  (16384 B)
  float* W2t = (float*)(ws + 16384);                    // 2048 f  ( 8192 B)
  unsigned short* Bhi = (unsigned short*)(ws + 24576);  // 47104 u16 (94208 B)
  unsigned short* Blo = (unsigned short*)(ws + 118784); // 47104 u16

  const int B = in_sizes[0] / 64;        // 32768

  prep_kernel<<<184, 256, 0, stream>>>(W1, W2, W3, W1t, W2t, Bhi, Blo);

  fused_kernel<<<B / 64, 512, 0, stream>>>(
      x, W1t, b1, W2t, b2, Bhi, Blo, b3, out, B);
}

// Round 12
// 135.264 us; speedup vs baseline: 1.3732x; 1.1362x over previous
//
#include <hip/hip_runtime.h>

#define NM 23        // 3*K - 1, K = 8

typedef short short8 __attribute__((ext_vector_type(8)));
typedef float f32x4 __attribute__((ext_vector_type(4)));

__device__ __forceinline__ float softplus_f(float v) {
  return fmaxf(v, 0.f) + __logf(1.f + __expf(-fabsf(v)));
}

__device__ __forceinline__ unsigned short bf16_rne(float x) {
  unsigned u = __float_as_uint(x);
  u += 0x7FFFu + ((u >> 16) & 1u);
  return (unsigned short)(u >> 16);
}

// ---------------------------------------------------------------------------
// Prep (R11-validated): pre-masked L1/L2 weights + W3 as MFMA B-fragments
// (bf16 hi/lo split). B[k][n]: n=lane&15, k=(lane>>4)*8+j; n = m*64+d.
// Stored lane-contiguous 16B. Coverage: 184*256 = 47104 exact.
// ---------------------------------------------------------------------------
__global__ __launch_bounds__(256) void prep_kernel(
    const float* __restrict__ W1, const float* __restrict__ W2,
    const float* __restrict__ W3,
    float* __restrict__ W1t, float* __restrict__ W2t,
    unsigned short* __restrict__ Bhi, unsigned short* __restrict__ Blo) {
  const int idx = blockIdx.x * 256 + threadIdx.x;
  if (idx < 64 * 64) {                  // W1t[d][i] = mask * W1[i][d]
    const int d = idx >> 6, i = idx & 63;
    W1t[idx] = ((i % 63) >= d) ? W1[i * 64 + d] : 0.f;
  }
  if (idx < 64 * 32) {                  // W2t[i][j] = mask * W2[j][i]
    const int i = idx >> 5, j = idx & 31;
    W2t[idx] = ((i % 63) <= j) ? W2[j * 64 + i] : 0.f;
  }
  if (idx < 92 * 64 * 8) {              // B fragments
    const int nt = idx >> 9;
    const int rem = idx & 511;
    const int lane = rem >> 3, j = rem & 7;
    const int col = lane & 15, quad = lane >> 4;
    const int n = nt * 16 + col;        // n = m*64 + d
    const int d = n & 63;
    const int k = quad * 8 + j;
    const float v = (k < d) ? W3[(size_t)n * 32 + k] : 0.f;
    const unsigned short h = bf16_rne(v);
    const float hf = __uint_as_float(((unsigned)h) << 16);
    Bhi[idx] = h;
    Blo[idx] = bf16_rne(v - hf);
  }
}

// ---------------------------------------------------------------------------
// Fused kernel: grid = (B/64)*2 = 1024 blocks; block = 64 rows x 32 d's,
// 256 threads (4 waves), lane = row for L1/L2 (wave-uniform s_load weights).
// L3: wave w = M-tile mt (rows mt*16..+15); dc in {ds*2, ds*2+1}. Per dc:
// 23 tiles x 3 MFMAs (bf16 hi/lo), bias pre-folded into acc init; spline
// consumes accumulators in-register (C: row=quad*4+reg, col=lane&15 --
// R11-validated). launch_bounds(256,3): VGPR cap 170 >= ~155 live -> NO
// SPILLS (R11: cap 128 < 150 live => 230 MB scratch traffic, the bottleneck).
// ---------------------------------------------------------------------------
__global__ __launch_bounds__(256, 3) void fused_kernel(
    const float* __restrict__ x,
    const float* __restrict__ W1t, const float* __restrict__ b1,
    const float* __restrict__ W2t, const float* __restrict__ b2,
    const unsigned short* __restrict__ Bhi,
    const unsigned short* __restrict__ Blo,
    const float* __restrict__ b3,
    float* __restrict__ out, float* __restrict__ ldws, int B) {
  __shared__ float xs[64][68];     // x in; z in-place for this block's d-half
  __shared__ float h1s[64][65];
  __shared__ float h2s[64][36];    // stride 36: 16B-aligned b128 A-frag reads
  __shared__ float b3s[32 * NM];   // this d-half's biases: [dl][m]

  const int t = threadIdx.x;
  const int rb = blockIdx.x >> 1;       // row-block
  const int ds = blockIdx.x & 1;        // d-half: d in [ds*32, ds*32+32)
  const int b0 = rb * 64;

  // ---- stage x: 64x64, 4 float4/thread, coalesced ----
  #pragma unroll
  for (int u = 0; u < 4; ++u) {
    const int idx = t + u * 256;
    const int rr = idx >> 4, c4 = (idx & 15) * 4;
    const float4 v = *reinterpret_cast<const float4*>(
        x + (size_t)b0 * 64 + (size_t)idx * 4);
    xs[rr][c4 + 0] = v.x; xs[rr][c4 + 1] = v.y;
    xs[rr][c4 + 2] = v.z; xs[rr][c4 + 3] = v.w;
  }
  // ---- stage b3 for this d-half: b3s[dl*NM+m] = b3[m*64 + ds*32 + dl] ----
  for (int idx = t; idx < 32 * NM; idx += 256) {
    const int dl = idx / NM, m = idx - dl * NM;
    b3s[idx] = b3[m * 64 + ds * 32 + dl];
  }
  __syncthreads();

  const int r  = t & 63;                                  // lane = row
  const int wv = __builtin_amdgcn_readfirstlane(t >> 6);  // wave 0..3

  // ---- layer 1: i in [wv*16, wv*16+16), pure fmac ----
  {
    const int iBase = wv * 16;
    float acc1[16];
    #pragma unroll
    for (int ii = 0; ii < 16; ++ii) acc1[ii] = b1[iBase + ii];
    #pragma unroll 4
    for (int dd = 0; dd < 64; ++dd) {
      const float xv = xs[r][dd];
      const float* wrow = W1t + dd * 64 + iBase;          // uniform s_load
      #pragma unroll
      for (int ii = 0; ii < 16; ++ii) acc1[ii] = fmaf(xv, wrow[ii], acc1[ii]);
    }
    #pragma unroll
    for (int ii = 0; ii < 16; ++ii) h1s[r][iBase + ii] = fmaxf(acc1[ii], 0.f);
  }
  __syncthreads();

  // ---- layer 2: j in [wv*8, wv*8+8), pure fmac ----
  {
    const int jBase = wv * 8;
    float acc2[8];
    #pragma unroll
    for (int jj = 0; jj < 8; ++jj) acc2[jj] = b2[jBase + jj];
    #pragma unroll 4
    for (int i2 = 0; i2 < 64; ++i2) {
      const float hv = h1s[r][i2];
      const float* wrow = W2t + i2 * 32 + jBase;          // uniform s_load
      #pragma unroll
      for (int jj = 0; jj < 8; ++jj) acc2[jj] = fmaf(hv, wrow[jj], acc2[jj]);
    }
    #pragma unroll
    for (int jj = 0; jj < 8; ++jj)
      h2s[r][jBase + jj] = fmaxf(acc2[jj], 0.f);
  }
  __syncthreads();

  // ---- MFMA layer 3 + spline ----
  const int lane = t & 63;
  const int mt   = wv;                  // M-tile: rows mt*16..mt*16+15
  const int col  = lane & 15;
  const int quad = lane >> 4;

  // A fragment: A[m=lane&15][k=quad*8+j] from h2, bf16 hi/lo split
  short8 ahi, alo;
  {
    const int arow = mt * 16 + col;
    const f32x4 a0 = *reinterpret_cast<const f32x4*>(&h2s[arow][quad * 8]);
    const f32x4 a1 = *reinterpret_cast<const f32x4*>(&h2s[arow][quad * 8 + 4]);
    float af[8] = {a0.x, a0.y, a0.z, a0.w, a1.x, a1.y, a1.z, a1.w};
    #pragma unroll
    for (int j = 0; j < 8; ++j) {
      const unsigned short h = bf16_rne(af[j]);
      ahi[j] = (short)h;
      alo[j] = (short)bf16_rne(af[j] - __uint_as_float(((unsigned)h) << 16));
    }
  }

  float ldr[4] = {0.f, 0.f, 0.f, 0.f};

  #pragma unroll 1
  for (int jj = 0; jj < 2; ++jj) {
    const int dc = ds * 2 + jj;                           // d-chunk 0..3
    const int d  = dc * 16 + col;                         // this lane's d
    const int dl = d - ds * 32;                           // 0..31

    // bias pre-folded into accumulator init (C = A*B + bias)
    f32x4 acc[NM];
    #pragma unroll
    for (int m = 0; m < NM; ++m) {
      const float bv = b3s[dl * NM + m];
      acc[m] = (f32x4){bv, bv, bv, bv};
    }
    #pragma unroll
    for (int m = 0; m < NM; ++m) {
      const int nt = 4 * m + dc;
      const size_t off = ((size_t)nt * 64 + lane) * 8;
      const short8 bh = *reinterpret_cast<const short8*>(Bhi + off);
      const short8 bl = *reinterpret_cast<const short8*>(Blo + off);
      acc[m] = __builtin_amdgcn_mfma_f32_16x16x32_bf16(ahi, bh, acc[m], 0, 0, 0);
      acc[m] = __builtin_amdgcn_mfma_f32_16x16x32_bf16(alo, bh, acc[m], 0, 0, 0);
      acc[m] = __builtin_amdgcn_mfma_f32_16x16x32_bf16(ahi, bl, acc[m], 0, 0, 0);
    }

    // spline: 4 rows per lane (C rows quad*4+reg), this lane's d
    #pragma unroll
    for (int reg = 0; reg < 4; ++reg) {
      const int row = mt * 16 + quad * 4 + reg;

      float p[NM];
      #pragma unroll
      for (int m = 0; m < NM; ++m) p[m] = acc[m][reg];

      const float xv = xs[row][d];
      const float xc = fminf(fmaxf(xv, -3.f), 3.f);

      float mw = p[0];
      #pragma unroll
      for (int k = 1; k < 8; ++k) mw = fmaxf(mw, p[k]);
      float ew[8], sw = 0.f;
      #pragma unroll
      for (int k = 0; k < 8; ++k) { ew[k] = __expf(p[k] - mw); sw += ew[k]; }
      const float invw = 1.f / sw;

      float mh = p[8];
      #pragma unroll
      for (int k = 1; k < 8; ++k) mh = fmaxf(mh, p[8 + k]);
      float eh[8], sh = 0.f;
      #pragma unroll
      for (int k = 0; k < 8; ++k) { eh[k] = __expf(p[8 + k] - mh); sh += eh[k]; }
      const float invh = 1.f / sh;

      const float WSC = 1.0f - 1e-3f * 8.0f;
      float cumw[9], cumh[9];
      cumw[0] = -3.f; cumh[0] = -3.f;
      float cw = 0.f, ch = 0.f;
      #pragma unroll
      for (int k = 0; k < 7; ++k) {
        cw += 1e-3f + WSC * (ew[k] * invw);
        ch += 1e-3f + WSC * (eh[k] * invh);
        cumw[k + 1] = fmaf(6.f, cw, -3.f);
        cumh[k + 1] = fmaf(6.f, ch, -3.f);
      }
      cumw[8] = 3.f; cumh[8] = 3.f;

      float derivs[9];
      derivs[0] = 1.f; derivs[8] = 1.f;
      #pragma unroll
      for (int k = 0; k < 7; ++k) derivs[k + 1] = 1e-3f + softplus_f(p[16 + k]);

      float xk = cumw[0], xk1 = cumw[1];
      float yk = cumh[0], yk1 = cumh[1];
      float dk = derivs[0], dk1 = derivs[1];
      #pragma unroll
      for (int k = 1; k < 8; ++k) {
        const bool s = xc >= cumw[k] + 1e-6f;
        xk  = s ? cumw[k]       : xk;
        xk1 = s ? cumw[k + 1]   : xk1;
        yk  = s ? cumh[k]       : yk;
        yk1 = s ? cumh[k + 1]   : yk1;
        dk  = s ? derivs[k]     : dk;
        dk1 = s ? derivs[k + 1] : dk1;
      }

      const float wk = xk1 - xk, hk = yk1 - yk;
      const float invwk = 1.f / wk;
      const float delta = hk * invwk;
      const float theta = (xc - xk) * invwk;
      const float omt = 1.f - theta;
      const float tt = theta * omt;
      const float th2 = theta * theta;
      const float num = hk * (delta * th2 + dk * tt);
      const float den = delta + (dk + dk1 - 2.f * delta) * tt;
      const float yv = yk + num / den;
      const float dnum = delta * delta * (dk1 * th2 + 2.f * delta * tt + dk * omt * omt);
      const float ldv = __logf(dnum) - 2.f * __logf(den);

      const bool inside = (xv >= -3.f) && (xv <= 3.f);
      xs[row][d] = inside ? yv : xv;        // z in-place (same owner lane)
      ldr[reg] += inside ? ldv : 0.f;
    }
  }

  // ---- log-det: reduce across the 16 cols (lane bits 0..3) ----
  #pragma unroll
  for (int mask = 1; mask <= 8; mask <<= 1) {
    #pragma unroll
    for (int reg = 0; reg < 4; ++reg)
      ldr[reg] += __shfl_xor(ldr[reg], mask, 64);
  }
  __syncthreads();   // all xs spline-writes done before z readback

  if (col == 0) {
    #pragma unroll
    for (int reg = 0; reg < 4; ++reg)
      ldws[(size_t)ds * B + b0 + mt * 16 + quad * 4 + reg] = ldr[reg];
  }

  // ---- coalesced z write: this block's 32 d-columns ----
  #pragma unroll
  for (int u = 0; u < 2; ++u) {
    const int idx = t + u * 256;
    const int rr = idx >> 3, c4 = (idx & 7) * 4;
    const float4 v = make_float4(xs[rr][ds * 32 + c4 + 0],
                                 xs[rr][ds * 32 + c4 + 1],
                                 xs[rr][ds * 32 + c4 + 2],
                                 xs[rr][ds * 32 + c4 + 3]);
    *reinterpret_cast<float4*>(
        out + (size_t)(b0 + rr) * 64 + ds * 32 + c4) = v;
  }
}

// ---------------------------------------------------------------------------
// Sum the 2 d-half log-det partials.
// ---------------------------------------------------------------------------
__global__ __launch_bounds__(256) void ld_reduce(
    const float* __restrict__ ldws, float* __restrict__ out, int B) {
  const int idx = blockIdx.x * 256 + threadIdx.x;
  if (idx < B) out[(size_t)B * 64 + idx] = ldws[idx] + ldws[B + idx];
}

extern "C" void kernel_launch(void* const* d_in, const int* in_sizes, int n_in,
                              void* d_out, int out_size, void* d_ws, size_t ws_size,
                              hipStream_t stream) {
  const float* x  = (const float*)d_in[0];
  const float* W1 = (const float*)d_in[1];
  const float* b1 = (const float*)d_in[2];
  const float* W2 = (const float*)d_in[3];
  const float* b2 = (const float*)d_in[4];
  const float* W3 = (const float*)d_in[5];
  const float* b3 = (const float*)d_in[6];
  float* out = (float*)d_out;
  char* ws   = (char*)d_ws;

  float* W1t = (float*)ws;                              // 4096 f
  float* W2t = (float*)(ws + 16384);                    // 2048 f
  unsigned short* Bhi = (unsigned short*)(ws + 24576);  // 47104 u16
  unsigned short* Blo = (unsigned short*)(ws + 118784); // 47104 u16
  float* ldws = (float*)(ws + 212992);                  // 2*B floats

  const int B = in_sizes[0] / 64;        // 32768

  prep_kernel<<<184, 256, 0, stream>>>(W1, W2, W3, W1t, W2t, Bhi, Blo);

  fused_kernel<<<(B / 64) * 2, 256, 0, stream>>>(
      x, W1t, b1, W2t, b2, Bhi, Blo, b3, out, ldws, B);

  ld_reduce<<<(B + 255) / 256, 256, 0, stream>>>(ldws, out, B);
}